// Round 1
// baseline (73.071 us; speedup 1.0000x reference)
//
#include <hip/hip_runtime.h>

#define DD 128
#define FF 512
#define BAGS 5000

// Monotonic uint key for f32: preserves float ordering under unsigned compare.
__device__ __forceinline__ unsigned fkey(float f) {
    unsigned u = __float_as_uint(f);
    return (u & 0x80000000u) ? ~u : (u | 0x80000000u);
}

// loc[row] = dot(z[row,:], W) + b. 32 lanes per row, float4 per lane.
__global__ void loc_kernel(const float* __restrict__ z, const float* __restrict__ W,
                           const float* __restrict__ b, float* __restrict__ loc, int N) {
    int lane = threadIdx.x & 31;
    long long row = (long long)blockIdx.x * 8 + (threadIdx.x >> 5);
    if (row >= N) return;
    float4 zv = ((const float4*)(z + row * DD))[lane];
    float4 wv = ((const float4*)W)[lane];
    float s = zv.x * wv.x + zv.y * wv.y + zv.z * wv.z + zv.w * wv.w;
    #pragma unroll
    for (int off = 16; off >= 1; off >>= 1) s += __shfl_xor(s, off, 32);
    if (lane == 0) loc[row] = s + b[0];
}

__global__ void init_kernel(unsigned* __restrict__ segmax, int* __restrict__ argm, int N) {
    int j = blockIdx.x * blockDim.x + threadIdx.x;
    if (j < BAGS) { segmax[j] = 0u; argm[j] = N; }
}

__global__ void segmax_kernel(const float* __restrict__ loc, const int* __restrict__ bag,
                              unsigned* __restrict__ segmax, int N) {
    int i = blockIdx.x * blockDim.x + threadIdx.x;
    if (i < N) atomicMax(&segmax[bag[i]], fkey(loc[i]));
}

__global__ void argmin_kernel(const float* __restrict__ loc, const int* __restrict__ bag,
                              const unsigned* __restrict__ segmax, int* __restrict__ argm, int N) {
    int i = blockIdx.x * blockDim.x + threadIdx.x;
    if (i < N) {
        int bg = bag[i];
        if (fkey(loc[i]) == segmax[bg]) atomicMin(&argm[bg], i);
    }
}

// One block per bag: copy the argmax row of each array (zeros if bag empty).
__global__ void gather_kernel(const float* __restrict__ z, const float* __restrict__ inst,
                              const float* __restrict__ mu, const float* __restrict__ stdv,
                              const float* __restrict__ loc, const int* __restrict__ argm,
                              float* __restrict__ oM, float* __restrict__ oInst,
                              float* __restrict__ oZ, float* __restrict__ oMu,
                              float* __restrict__ oStd, int N) {
    int bagi = blockIdx.x;
    int a = argm[bagi];
    bool empty = (a >= N);
    long long ac = empty ? 0 : a;
    const float4 zero4 = make_float4(0.f, 0.f, 0.f, 0.f);
    int t = threadIdx.x;
    if (t < 128) {
        float4 v = empty ? zero4 : ((const float4*)(inst + ac * FF))[t];
        ((float4*)(oInst + (long long)bagi * FF))[t] = v;
    } else if (t < 160) {
        int k = t - 128;
        float4 v = empty ? zero4 : ((const float4*)(z + ac * DD))[k];
        ((float4*)(oZ + (long long)bagi * DD))[k] = v;
    } else if (t < 192) {
        int k = t - 160;
        float4 v = empty ? zero4 : ((const float4*)(mu + ac * DD))[k];
        ((float4*)(oMu + (long long)bagi * DD))[k] = v;
    } else if (t < 224) {
        int k = t - 192;
        float4 v = empty ? zero4 : ((const float4*)(stdv + ac * DD))[k];
        ((float4*)(oStd + (long long)bagi * DD))[k] = v;
    } else if (t == 224) {
        oM[bagi] = empty ? 0.f : loc[a];
    }
}

extern "C" void kernel_launch(void* const* d_in, const int* in_sizes, int n_in,
                              void* d_out, int out_size, void* d_ws, size_t ws_size,
                              hipStream_t stream) {
    const float* z    = (const float*)d_in[0];
    const int*   bag  = (const int*)d_in[1];
    const float* inst = (const float*)d_in[2];
    const float* mu   = (const float*)d_in[3];
    const float* stdv = (const float*)d_in[4];
    const float* W    = (const float*)d_in[5];
    const float* b    = (const float*)d_in[6];
    int N = in_sizes[1];                 // bag_idx element count

    float* out = (float*)d_out;
    // Output layout (flat, return order): M | max_instances | max_z_ins | loc_ins | mu | std
    long long off_inst = BAGS;
    long long off_z    = off_inst + (long long)BAGS * FF;
    long long off_loc  = off_z    + (long long)BAGS * DD;
    long long off_mu   = off_loc  + N;
    long long off_std  = off_mu   + (long long)BAGS * DD;

    unsigned* segmax = (unsigned*)d_ws;
    int*      argm   = (int*)((char*)d_ws + BAGS * sizeof(unsigned));
    float*    loc    = out + off_loc;

    loc_kernel<<<(N + 7) / 8, 256, 0, stream>>>(z, W, b, loc, N);
    init_kernel<<<(BAGS + 255) / 256, 256, 0, stream>>>(segmax, argm, N);
    segmax_kernel<<<(N + 255) / 256, 256, 0, stream>>>(loc, bag, segmax, N);
    argmin_kernel<<<(N + 255) / 256, 256, 0, stream>>>(loc, bag, segmax, argm, N);
    gather_kernel<<<BAGS, 256, 0, stream>>>(z, inst, mu, stdv, loc, argm,
                                            out, out + off_inst, out + off_z,
                                            out + off_mu, out + off_std, N);
}

// Round 2
// 68.395 us; speedup vs baseline: 1.0684x; 1.0684x over previous
//
#include <hip/hip_runtime.h>

#define DD 128
#define FF 512
#define BAGS 5000

// Monotonic uint key for f32: preserves float ordering under unsigned compare.
__device__ __forceinline__ unsigned fkey(float f) {
    unsigned u = __float_as_uint(f);
    return (u & 0x80000000u) ? ~u : (u | 0x80000000u);
}
// Inverse of fkey (bijective).
__device__ __forceinline__ float fkey_inv(unsigned k) {
    unsigned u = (k & 0x80000000u) ? (k & 0x7FFFFFFFu) : ~k;
    return __uint_as_float(u);
}

__global__ void init_kernel(unsigned long long* __restrict__ packed) {
    int j = blockIdx.x * blockDim.x + threadIdx.x;
    if (j < BAGS) packed[j] = 0ull;
}

// loc[row] = dot(z[row,:], W) + b; fused 64-bit atomicMax of (fkey(loc), N-1-row).
// Max picks largest loc; among bit-equal loc, smallest row index (reference tie-break).
__global__ void loc_max_kernel(const float* __restrict__ z, const float* __restrict__ W,
                               const float* __restrict__ b, const int* __restrict__ bag,
                               float* __restrict__ loc,
                               unsigned long long* __restrict__ packed, int N) {
    int lane = threadIdx.x & 31;
    long long row = (long long)blockIdx.x * 8 + (threadIdx.x >> 5);
    if (row >= N) return;
    float4 zv = ((const float4*)(z + row * DD))[lane];
    float4 wv = ((const float4*)W)[lane];
    float s = zv.x * wv.x + zv.y * wv.y + zv.z * wv.z + zv.w * wv.w;
    #pragma unroll
    for (int off = 16; off >= 1; off >>= 1) s += __shfl_xor(s, off, 32);
    if (lane == 0) {
        s += b[0];
        loc[row] = s;
        unsigned long long key =
            ((unsigned long long)fkey(s) << 32) | (unsigned)(N - 1 - (int)row);
        atomicMax(&packed[bag[row]], key);
    }
}

// One block per bag: copy the argmax row of each array (zeros if bag empty).
__global__ void gather_kernel(const float* __restrict__ z, const float* __restrict__ inst,
                              const float* __restrict__ mu, const float* __restrict__ stdv,
                              const unsigned long long* __restrict__ packed,
                              float* __restrict__ oM, float* __restrict__ oInst,
                              float* __restrict__ oZ, float* __restrict__ oMu,
                              float* __restrict__ oStd, int N) {
    int bagi = blockIdx.x;
    unsigned long long p = packed[bagi];
    bool empty = (p == 0ull);
    long long ac = empty ? 0 : (long long)(N - 1 - (int)(unsigned)(p & 0xFFFFFFFFull));
    const float4 zero4 = make_float4(0.f, 0.f, 0.f, 0.f);
    int t = threadIdx.x;
    if (t < 128) {
        float4 v = empty ? zero4 : ((const float4*)(inst + ac * FF))[t];
        ((float4*)(oInst + (long long)bagi * FF))[t] = v;
    } else if (t < 160) {
        int k = t - 128;
        float4 v = empty ? zero4 : ((const float4*)(z + ac * DD))[k];
        ((float4*)(oZ + (long long)bagi * DD))[k] = v;
    } else if (t < 192) {
        int k = t - 160;
        float4 v = empty ? zero4 : ((const float4*)(mu + ac * DD))[k];
        ((float4*)(oMu + (long long)bagi * DD))[k] = v;
    } else if (t < 224) {
        int k = t - 192;
        float4 v = empty ? zero4 : ((const float4*)(stdv + ac * DD))[k];
        ((float4*)(oStd + (long long)bagi * DD))[k] = v;
    } else if (t == 224) {
        oM[bagi] = empty ? 0.f : fkey_inv((unsigned)(p >> 32));
    }
}

extern "C" void kernel_launch(void* const* d_in, const int* in_sizes, int n_in,
                              void* d_out, int out_size, void* d_ws, size_t ws_size,
                              hipStream_t stream) {
    const float* z    = (const float*)d_in[0];
    const int*   bag  = (const int*)d_in[1];
    const float* inst = (const float*)d_in[2];
    const float* mu   = (const float*)d_in[3];
    const float* stdv = (const float*)d_in[4];
    const float* W    = (const float*)d_in[5];
    const float* b    = (const float*)d_in[6];
    int N = in_sizes[1];

    float* out = (float*)d_out;
    // Output layout (flat, return order): M | max_instances | max_z_ins | loc_ins | mu | std
    long long off_inst = BAGS;
    long long off_z    = off_inst + (long long)BAGS * FF;
    long long off_loc  = off_z    + (long long)BAGS * DD;
    long long off_mu   = off_loc  + N;
    long long off_std  = off_mu   + (long long)BAGS * DD;

    unsigned long long* packed = (unsigned long long*)d_ws;
    float* loc = out + off_loc;

    init_kernel<<<(BAGS + 255) / 256, 256, 0, stream>>>(packed);
    loc_max_kernel<<<(N + 7) / 8, 256, 0, stream>>>(z, W, b, bag, loc, packed, N);
    gather_kernel<<<BAGS, 256, 0, stream>>>(z, inst, mu, stdv, packed,
                                            out, out + off_inst, out + off_z,
                                            out + off_mu, out + off_std, N);
}

// Round 3
// 45.315 us; speedup vs baseline: 1.6125x; 1.5093x over previous
//
#include <hip/hip_runtime.h>

#define DD 128
#define FF 512
#define BAGS 5000
#define RPG 16   // consecutive rows per 32-lane group

// Monotonic uint key for f32: preserves float ordering under unsigned compare.
__device__ __forceinline__ unsigned fkey(float f) {
    unsigned u = __float_as_uint(f);
    return (u & 0x80000000u) ? ~u : (u | 0x80000000u);
}
// Inverse of fkey (bijective).
__device__ __forceinline__ float fkey_inv(unsigned k) {
    unsigned u = (k & 0x80000000u) ? (k & 0x7FFFFFFFu) : ~k;
    return __uint_as_float(u);
}

__global__ void init_kernel(unsigned long long* __restrict__ packed) {
    int j = blockIdx.x * blockDim.x + threadIdx.x;
    if (j < BAGS) packed[j] = 0ull;
}

// Each 32-lane group computes loc for RPG consecutive rows (sorted bag_idx =>
// mostly one bag per group); running max in registers, atomic only on bag change.
__global__ void loc_max_kernel(const float* __restrict__ z, const float* __restrict__ W,
                               const float* __restrict__ b, const int* __restrict__ bag,
                               float* __restrict__ loc,
                               unsigned long long* __restrict__ packed, int N) {
    int lane = threadIdx.x & 31;
    long long gidx = (long long)blockIdx.x * (blockDim.x >> 5) + (threadIdx.x >> 5);
    long long row0 = gidx * RPG;
    if (row0 >= N) return;
    float4 wv = ((const float4*)W)[lane];
    float bb = b[0];
    int rcnt = (int)((N - row0 < RPG) ? (N - row0) : RPG);

    unsigned long long best = 0ull;
    int curbag = -1;
    for (int j = 0; j < rcnt; ++j) {
        long long row = row0 + j;
        float4 zv = ((const float4*)(z + row * DD))[lane];
        float s = zv.x * wv.x + zv.y * wv.y + zv.z * wv.z + zv.w * wv.w;
        #pragma unroll
        for (int off = 16; off >= 1; off >>= 1) s += __shfl_xor(s, off, 32);
        if (lane == 0) {
            s += bb;
            loc[row] = s;
            unsigned long long key =
                ((unsigned long long)fkey(s) << 32) | (unsigned)(N - 1 - (int)row);
            int bg = bag[row];
            if (bg != curbag) {
                if (curbag >= 0) atomicMax(&packed[curbag], best);
                curbag = bg;
                best = key;
            } else if (key > best) {
                best = key;
            }
        }
    }
    if (lane == 0 && curbag >= 0) atomicMax(&packed[curbag], best);
}

// One block per bag: copy the argmax row of each array (zeros if bag empty).
__global__ void gather_kernel(const float* __restrict__ z, const float* __restrict__ inst,
                              const float* __restrict__ mu, const float* __restrict__ stdv,
                              const unsigned long long* __restrict__ packed,
                              float* __restrict__ oM, float* __restrict__ oInst,
                              float* __restrict__ oZ, float* __restrict__ oMu,
                              float* __restrict__ oStd, int N) {
    int bagi = blockIdx.x;
    unsigned long long p = packed[bagi];
    bool empty = (p == 0ull);
    long long ac = empty ? 0 : (long long)(N - 1 - (int)(unsigned)(p & 0xFFFFFFFFull));
    const float4 zero4 = make_float4(0.f, 0.f, 0.f, 0.f);
    int t = threadIdx.x;
    if (t < 128) {
        float4 v = empty ? zero4 : ((const float4*)(inst + ac * FF))[t];
        ((float4*)(oInst + (long long)bagi * FF))[t] = v;
    } else if (t < 160) {
        int k = t - 128;
        float4 v = empty ? zero4 : ((const float4*)(z + ac * DD))[k];
        ((float4*)(oZ + (long long)bagi * DD))[k] = v;
    } else if (t < 192) {
        int k = t - 160;
        float4 v = empty ? zero4 : ((const float4*)(mu + ac * DD))[k];
        ((float4*)(oMu + (long long)bagi * DD))[k] = v;
    } else if (t < 224) {
        int k = t - 192;
        float4 v = empty ? zero4 : ((const float4*)(stdv + ac * DD))[k];
        ((float4*)(oStd + (long long)bagi * DD))[k] = v;
    } else if (t == 224) {
        oM[bagi] = empty ? 0.f : fkey_inv((unsigned)(p >> 32));
    }
}

extern "C" void kernel_launch(void* const* d_in, const int* in_sizes, int n_in,
                              void* d_out, int out_size, void* d_ws, size_t ws_size,
                              hipStream_t stream) {
    const float* z    = (const float*)d_in[0];
    const int*   bag  = (const int*)d_in[1];
    const float* inst = (const float*)d_in[2];
    const float* mu   = (const float*)d_in[3];
    const float* stdv = (const float*)d_in[4];
    const float* W    = (const float*)d_in[5];
    const float* b    = (const float*)d_in[6];
    int N = in_sizes[1];

    float* out = (float*)d_out;
    // Output layout (flat, return order): M | max_instances | max_z_ins | loc_ins | mu | std
    long long off_inst = BAGS;
    long long off_z    = off_inst + (long long)BAGS * FF;
    long long off_loc  = off_z    + (long long)BAGS * DD;
    long long off_mu   = off_loc  + N;
    long long off_std  = off_mu   + (long long)BAGS * DD;

    unsigned long long* packed = (unsigned long long*)d_ws;
    float* loc = out + off_loc;

    init_kernel<<<(BAGS + 255) / 256, 256, 0, stream>>>(packed);
    long long groups = ((long long)N + RPG - 1) / RPG;
    int blocks = (int)((groups + 7) / 8);
    loc_max_kernel<<<blocks, 256, 0, stream>>>(z, W, b, bag, loc, packed, N);
    gather_kernel<<<BAGS, 256, 0, stream>>>(z, inst, mu, stdv, packed,
                                            out, out + off_inst, out + off_z,
                                            out + off_mu, out + off_std, N);
}